// Round 6
// baseline (157.363 us; speedup 1.0000x reference)
//
#include <hip/hip_runtime.h>

// Problem constants (from reference): B=4, N=2048, IN_F=512, HEADS=8, D=64
#define BB   4
#define NN   2048
#define INF  512
#define HH   8
#define DD   64
#define BH   (BB*HH)   // 32
#define NCK  16        // 128-row chunks per (b,h)
#define CKS  128       // chunk size
#define KSP  8         // k-split for V GEMM

// ============================================================================
// A[b,h,i,j] = softmax_j( leaky_relu(q_j + k_i) ), H = A @ V.
// exp(leaky(x)) is piecewise multiplicative; sort j by q_j and the softmax
// collapses to prefix sums + binary search. O(N·D).
// R5 learned: harness 0xAA ws-poison (2x43us) is inside dur_us — floor ~95us.
// R6: (1) V GEMM with W in VGPRs + X via wave-uniform SMEM loads (no LDS, no
// barriers — R5 version was LDS-pipe-bound); (2) k_sort drops barriers for
// stride<=64 stages (wave-owned 128-elem segments, per-wave DS is in-order).
// ============================================================================

// -------- Kernel 1a: V partials. wave = 16 rows x 64-k slice; lane = d ------
__global__ __launch_bounds__(256) void k_vpart(
    const float* __restrict__ X, const float* __restrict__ Wv,
    float* __restrict__ Vpart)   // [KSP][BB*NN][DD]
{
  const int t   = threadIdx.x;
  const int d   = t & 63;
  const int wid = __builtin_amdgcn_readfirstlane(blockIdx.x * 4 + (t >> 6));
  const int rg  = wid >> 3;          // 0..511: 16-row group
  const int ks  = wid & 7;           // k slice
  const int k0  = ks * 64;
  // W column d for 64 k's -> VGPRs (coalesced 256B loads, L2-hot)
  float wreg[64];
  const float* wp = Wv + (size_t)k0 * DD + d;
  #pragma unroll
  for (int kk = 0; kk < 64; kk++) wreg[kk] = wp[(size_t)kk * DD];
  // X row chunks are wave-uniform -> SMEM (s_load) pipe, no vmem/LDS in loop
  const float* xp = X + (size_t)(rg * 16) * INF + k0;
  float* vp = Vpart + ((size_t)ks * (BB*NN) + (size_t)rg * 16) * DD + d;
  for (int r = 0; r < 16; r++) {
    float a0 = 0.f, a1 = 0.f, a2 = 0.f, a3 = 0.f;
    #pragma unroll
    for (int kk = 0; kk < 64; kk += 4) {
      a0 += xp[kk+0] * wreg[kk+0];
      a1 += xp[kk+1] * wreg[kk+1];
      a2 += xp[kk+2] * wreg[kk+2];
      a3 += xp[kk+3] * wreg[kk+3];
    }
    vp[(size_t)r * DD] = (a0 + a1) + (a2 + a3);
    xp += INF;
  }
}

// -------- Kernel 1b: V = sum(partials)+bv ; q,k scalar scores ---------------
__global__ __launch_bounds__(256) void k_vred(
    const float* __restrict__ Vpart, const float* __restrict__ bv,
    const float* __restrict__ Wq, const float* __restrict__ bq,
    const float* __restrict__ Wk, const float* __restrict__ bk,
    float* __restrict__ V, float* __restrict__ qsg, float* __restrict__ ksg)
{
  __shared__ float Vs[16][DD + 1];
  const int t  = threadIdx.x;
  const size_t e0 = ((size_t)blockIdx.x * 256 + t) * 4;   // float4 granule
  const size_t STR = (size_t)BB * NN * DD;
  float4 a = *(const float4*)(Vpart + e0);
  #pragma unroll
  for (int p = 1; p < KSP; p++) {
    const float4 b = *(const float4*)(Vpart + (size_t)p * STR + e0);
    a.x += b.x;  a.y += b.y;  a.z += b.z;  a.w += b.w;
  }
  const float4 bb = *(const float4*)(bv + (e0 & 63));
  a.x += bb.x;  a.y += bb.y;  a.z += bb.z;  a.w += bb.w;
  *(float4*)(V + e0) = a;
  const int lrow = t >> 4;
  const int lcol = (t * 4) & 63;
  Vs[lrow][lcol]   = a.x;  Vs[lrow][lcol+1] = a.y;
  Vs[lrow][lcol+2] = a.z;  Vs[lrow][lcol+3] = a.w;
  __syncthreads();
  // q,k: 16 rows x 8 heads x {q,k} = 256 tasks, 1 per thread
  const int row = t >> 4;
  const int h   = t & 7;
  const bool isK = (t & 8) != 0;
  const float* W = isK ? Wk : Wq;
  float s = isK ? bk[h] : bq[h];
  #pragma unroll 8
  for (int dd = 0; dd < DD; dd++) s += Vs[row][dd] * W[dd*HH + h];
  const int grow = blockIdx.x * 16 + row;
  const int b = grow >> 11, n = grow & (NN - 1);
  (isK ? ksg : qsg)[(b*HH + h) * NN + n] = s;
}

// ---------------- Kernel 2: bitonic sort of q per (b,h), in-place ------------
// Stages with stride<=64 touch only a wave-owned 128-elem segment: per-wave
// DS ops retire in order -> no barrier needed for those stages.
__global__ __launch_bounds__(1024) void k_sort(
    float* __restrict__ q, unsigned short* __restrict__ idxg)
{
  __shared__ float key[NN];   // 8 KB
  __shared__ int   idx[NN];   // 8 KB
  const int t  = threadIdx.x;
  const int bh = blockIdx.x;
  key[t]        = q[bh*NN + t];        idx[t]        = t;
  key[t + 1024] = q[bh*NN + t + 1024]; idx[t + 1024] = t + 1024;
  __syncthreads();

#define CEX_STAGE(size, stride)                                         \
  {                                                                     \
    const int i = ((t & ~((stride) - 1)) << 1) | (t & ((stride) - 1));  \
    const int j = i + (stride);                                         \
    const bool up = ((i & (size)) == 0);                                \
    const float a = key[i], b = key[j];                                 \
    if (up ? (a > b) : (a < b)) {                                       \
      key[i] = b; key[j] = a;                                           \
      const int tmp = idx[i]; idx[i] = idx[j]; idx[j] = tmp;            \
    }                                                                   \
  }

  // phase A: sizes 2..128 — all strides <=64, wave-local, no barriers
  for (int size = 2; size <= 128; size <<= 1)
    for (int stride = size >> 1; stride > 0; stride >>= 1)
      CEX_STAGE(size, stride)
  __syncthreads();
  // phase B: sizes 256..2048 — barrier only for strides >=128
  for (int size = 256; size <= 2048; size <<= 1) {
    for (int stride = size >> 1; stride >= 128; stride >>= 1) {
      CEX_STAGE(size, stride)
      __syncthreads();
    }
    for (int stride = 64; stride > 0; stride >>= 1)
      CEX_STAGE(size, stride)
    __syncthreads();
  }
#undef CEX_STAGE

  q[bh*NN + t]        = key[t];
  q[bh*NN + t + 1024] = key[t + 1024];
  idxg[bh*NN + t]        = (unsigned short)idx[t];
  idxg[bh*NN + t + 1024] = (unsigned short)idx[t + 1024];
}

// -------- Kernel 3: hierarchical scan — chunk-local prefixes + chunk sums ----
__global__ __launch_bounds__(256) void k_scan(
    const float* __restrict__ sq, const unsigned short* __restrict__ idxg,
    const float* __restrict__ V,
    float* __restrict__ P1, float* __restrict__ P2,
    float* __restrict__ l1, float* __restrict__ l2,
    float* __restrict__ S1g, float* __restrict__ S2g,
    float* __restrict__ SL1, float* __restrict__ SL2)
{
  __shared__ float ss1[4][64], ss2[4][64], sl1[4], sl2[4];
  const int t  = threadIdx.x;
  const int bh = blockIdx.x >> 4;
  const int ck = blockIdx.x & 15;
  const int d  = t & 63, g = t >> 6;
  const int r0 = ck*CKS + g*32;
  const float* Vb  = V + (size_t)(bh >> 3) * NN * DD;
  const float* sqb = sq + bh*NN;
  const unsigned short* ib = idxg + bh*NN;
  float a1 = 0.f, a2 = 0.f, s1 = 0.f, s2 = 0.f;
  #pragma unroll 8
  for (int rr = 0; rr < 32; rr++) {
    const int r = r0 + rr;
    const float qv = sqb[r];
    const float e1 = __expf(qv), e2 = __expf(0.01f*qv);
    const float v  = Vb[(size_t)ib[r]*DD + d];
    a1 += e1*v;  a2 += e2*v;  s1 += e1;  s2 += e2;
  }
  ss1[g][d] = a1;  ss2[g][d] = a2;
  if (d == 0) { sl1[g] = s1;  sl2[g] = s2; }
  __syncthreads();
  float o1 = 0.f, o2 = 0.f, lo1 = 0.f, lo2 = 0.f;
  for (int gg = 0; gg < g; gg++) { o1 += ss1[gg][d]; o2 += ss2[gg][d]; lo1 += sl1[gg]; lo2 += sl2[gg]; }
  if (g == 0) {   // chunk totals -> scratch (lives in d_out, dead before k_out)
    S1g[(bh*NCK + ck)*64 + d] = ss1[0][d]+ss1[1][d]+ss1[2][d]+ss1[3][d];
    S2g[(bh*NCK + ck)*64 + d] = ss2[0][d]+ss2[1][d]+ss2[2][d]+ss2[3][d];
    if (d == 0) {
      SL1[bh*NCK + ck] = sl1[0]+sl1[1]+sl1[2]+sl1[3];
      SL2[bh*NCK + ck] = sl2[0]+sl2[1]+sl2[2]+sl2[3];
    }
  }
  // pass 2: store exclusive chunk-local prefixes (V re-load is L2-hot)
  a1 = o1; a2 = o2; s1 = lo1; s2 = lo2;
  float* P1b = P1 + (size_t)bh*NN*DD;
  float* P2b = P2 + (size_t)bh*NN*DD;
  #pragma unroll 8
  for (int rr = 0; rr < 32; rr++) {
    const int r = r0 + rr;
    const float qv = sqb[r];
    const float e1 = __expf(qv), e2 = __expf(0.01f*qv);
    const float v  = Vb[(size_t)ib[r]*DD + d];
    P1b[(size_t)r*DD + d] = a1;
    P2b[(size_t)r*DD + d] = a2;
    if (d == 0) { l1[bh*NN + r] = s1;  l2[bh*NN + r] = s2; }
    a1 += e1*v;  a2 += e2*v;  s1 += e1;  s2 += e2;
  }
}

// ---------- Kernel 4: fp64 scan of the 16 chunk sums -> chunk offsets --------
__global__ __launch_bounds__(256) void k_off(
    const float* __restrict__ S1g, const float* __restrict__ S2g,
    const float* __restrict__ SL1, const float* __restrict__ SL2,
    float* __restrict__ Off1, float* __restrict__ Off2,
    float* __restrict__ Loff1, float* __restrict__ Loff2)
{
  const int bh = blockIdx.x;
  const int t  = threadIdx.x;
  if (t < 128) {
    const int d = t & 63;
    const bool h2 = t >= 64;
    const float* S = h2 ? S2g : S1g;
    float* O = h2 ? Off2 : Off1;
    double a = 0.0;
    for (int ck = 0; ck < NCK; ck++) {
      O[((size_t)bh*(NCK+1) + ck)*64 + d] = (float)a;
      a += (double)S[((size_t)bh*NCK + ck)*64 + d];
    }
    O[((size_t)bh*(NCK+1) + NCK)*64 + d] = (float)a;
  } else if (t == 128 || t == 129) {
    const bool h2 = (t == 129);
    const float* S = h2 ? SL2 : SL1;
    float* O = h2 ? Loff2 : Loff1;
    double a = 0.0;
    for (int ck = 0; ck < NCK; ck++) { O[bh*(NCK+1) + ck] = (float)a; a += (double)S[bh*NCK + ck]; }
    O[bh*(NCK+1) + NCK] = (float)a;
  }
}

// ------- Kernel 5: 64-ary search (2 rounds) + combine + write ----------------
__global__ __launch_bounds__(256) void k_out(
    const float* __restrict__ sq, const float* __restrict__ ksg,
    const float* __restrict__ P1, const float* __restrict__ P2,
    const float* __restrict__ Off1, const float* __restrict__ Off2,
    const float* __restrict__ l1, const float* __restrict__ l2,
    const float* __restrict__ Loff1, const float* __restrict__ Loff2,
    float* __restrict__ out)
{
  const int t  = threadIdx.x;
  const int bh = blockIdx.x >> 9;
  const int i  = ((blockIdx.x & 511) << 2) + (t >> 6);
  const int d  = t & 63;                      // == lane id within wave
  const int b  = bh >> 3, h = bh & 7;
  const float kv = ksg[bh*NN + i];
  const float tt = -kv;
  const float* s = sq + bh*NN;
  // round 1: lane d probes block-of-32 boundary; sorted => ballot contiguous
  const unsigned long long m1 = __ballot(s[d*32 + 31] <= tt);
  const int c1 = __popcll(m1);
  int pos;
  if (c1 == 64) pos = NN;
  else {
    const int bs = c1 << 5;
    const unsigned long long m2 = __ballot(s[bs + (d & 31)] <= tt);
    pos = bs + (__popcll(m2) >> 1);   // both wave halves probe identically
  }
  const float ek  = __expf(kv);
  const float ek2 = __expf(0.01f * kv);
  const size_t base = (size_t)bh * NN * DD;
  const float T1  = Off1[((size_t)bh*(NCK+1) + NCK)*64 + d];
  const float Lt1 = Loff1[bh*(NCK+1) + NCK];
  float p1v, p2v, q1v, q2v;
  if (pos < NN) {   // wave-uniform
    const int ch = pos >> 7;
    p1v = P1[base + (size_t)pos*DD + d] + Off1[((size_t)bh*(NCK+1) + ch)*64 + d];
    p2v = P2[base + (size_t)pos*DD + d] + Off2[((size_t)bh*(NCK+1) + ch)*64 + d];
    q1v = l1[bh*NN + pos] + Loff1[bh*(NCK+1) + ch];
    q2v = l2[bh*NN + pos] + Loff2[bh*(NCK+1) + ch];
  } else {
    p1v = T1;   p2v = Off2[((size_t)bh*(NCK+1) + NCK)*64 + d];
    q1v = Lt1;  q2v = Loff2[bh*(NCK+1) + NCK];
  }
  const float num = ek * (T1 - p1v)  + ek2 * p2v;
  const float den = ek * (Lt1 - q1v) + ek2 * q2v;
  out[((size_t)(b*NN + i)) * (HH*DD) + h*DD + d] = num / den;
}

extern "C" void kernel_launch(void* const* d_in, const int* in_sizes, int n_in,
                              void* d_out, int out_size, void* d_ws, size_t ws_size,
                              hipStream_t stream)
{
  (void)in_sizes; (void)n_in; (void)out_size; (void)ws_size;
  const float* X  = (const float*)d_in[0];
  const float* Wv = (const float*)d_in[1];
  const float* bv = (const float*)d_in[2];
  const float* Wq = (const float*)d_in[3];
  const float* bq = (const float*)d_in[4];
  const float* Wk = (const float*)d_in[5];
  const float* bk = (const float*)d_in[6];
  float* out = (float*)d_out;

  // workspace carve-up (~36.95 MB, within proven budget)
  float* w = (float*)d_ws;
  float* V     = w;  w += (size_t)BB*NN*DD;        // 524288
  float* qsg   = w;  w += BH*NN;                   // sorted in-place -> sq
  float* ksg   = w;  w += BH*NN;
  float* l1    = w;  w += BH*NN;
  float* l2    = w;  w += BH*NN;
  unsigned short* idxg = (unsigned short*)w;  w += BH*NN/2;   // ushort
  float* Off1  = w;  w += BH*(NCK+1)*DD;
  float* Off2  = w;  w += BH*(NCK+1)*DD;
  float* Loff1 = w;  w += BH*(NCK+1);
  float* Loff2 = w;  w += BH*(NCK+1);
  float* P1    = w;  w += (size_t)BH*NN*DD;        // 4194304 (16 MB)
  float* P2    = w;  w += (size_t)BH*NN*DD;

  // V partials live in P1's space (dead until k_scan): 8 x 2 MB = 16 MB
  float* Vpart = P1;

  // chunk-sum scratch lives in d_out: dead before k_out fully overwrites it
  float* S1g = out;                 // 32768
  float* S2g = S1g + BH*NCK*DD;     // 32768
  float* SL1 = S2g + BH*NCK*DD;     // 512
  float* SL2 = SL1 + BH*NCK;        // 512

  k_vpart<<<1024, 256, 0, stream>>>(X, Wv, Vpart);
  k_vred <<<512, 256, 0, stream>>>(Vpart, bv, Wq, bq, Wk, bk, V, qsg, ksg);
  k_sort <<<BH, 1024, 0, stream>>>(qsg, idxg);
  k_scan <<<BH*NCK, 256, 0, stream>>>(qsg, idxg, V, P1, P2, l1, l2, S1g, S2g, SL1, SL2);
  k_off  <<<BH, 256, 0, stream>>>(S1g, S2g, SL1, SL2, Off1, Off2, Loff1, Loff2);
  k_out  <<<BH*512, 256, 0, stream>>>(qsg, ksg, P1, P2, Off1, Off2, l1, l2, Loff1, Loff2, out);
}

// Round 7
// 143.138 us; speedup vs baseline: 1.0994x; 1.0994x over previous
//
#include <hip/hip_runtime.h>

// Problem constants (from reference): B=4, N=2048, IN_F=512, HEADS=8, D=64
#define BB   4
#define NN   2048
#define INF  512
#define HH   8
#define DD   64
#define BH   (BB*HH)   // 32
#define NCK  16        // 128-row chunks per (b,h)
#define CKS  128       // chunk size
#define KSP  4         // k-split for V GEMM

// ============================================================================
// A[b,h,i,j] = softmax_j( leaky_relu(q_j + k_i) ), H = A @ V.
// exp(leaky(x)) is piecewise multiplicative; sort j by q_j and the softmax
// collapses to prefix sums + binary search. O(N·D).
// R5 learned: harness 0xAA ws-poison (~45us) is inside dur_us — floor ~95us.
// R7: V GEMM as register-tiled 4x4 LDS GEMM (the only shape that is
// VALU-bound per-k: 16 FMA (32cyc) vs 4 bcast b32 + 1 b128 (~35cyc LDS,
// overlapping pipe)). 512 blocks, 4 waves/SIMD. KSP back to 4.
// ============================================================================

// -------- Kernel 1a: V partials. block = 64 rows x 64 cols x 128 k ----------
__global__ __launch_bounds__(256) void k_v(
    const float* __restrict__ X, const float* __restrict__ Wv,
    float* __restrict__ Vpart)   // [KSP][BB*NN][DD]
{
  __shared__ float Xs[64][68];   // [row][k], pad 68 — 17.4 KB
  __shared__ float Ws[64][68];   // [k][d],   pad 68 — 17.4 KB
  const int t  = threadIdx.x;
  const int tr = t >> 4;         // 0..15 -> rows 4tr..4tr+3
  const int tc = t & 15;         // 0..15 -> cols 4tc..4tc+3
  const int rg = blockIdx.x >> 2;   // 0..127
  const int ks = blockIdx.x & 3;    // k quarter
  const int r0 = rg * 64;
  const int k0 = ks * 128;
  float acc[4][4] = {{0.f}};

  for (int kc = k0; kc < k0 + 128; kc += 64) {
    __syncthreads();
    // stage X 64x64 chunk [row][k] and Wv 64x64 chunk [k][d]; both coalesced
    // float4, conflict-free LDS writes (sequential addresses).
    #pragma unroll
    for (int i = 0; i < 4; i++) {
      const int e  = t + i * 256;       // 1024 float4 tasks each
      const int rw = e >> 4;            // 0..63
      const int c4 = (e & 15) * 4;      // 0..60
      *(float4*)(&Xs[rw][c4]) = *(const float4*)(X  + (size_t)(r0 + rw) * INF + kc + c4);
      *(float4*)(&Ws[rw][c4]) = *(const float4*)(Wv + (size_t)(kc + rw) * DD  + c4);
    }
    __syncthreads();
    #pragma unroll 8
    for (int k = 0; k < 64; k++) {
      const float4 w4 = *(const float4*)(&Ws[k][tc * 4]);  // 2-way (free)
      const float x0 = Xs[tr*4+0][k];   // 4 distinct addrs, 4 banks: bcast
      const float x1 = Xs[tr*4+1][k];
      const float x2 = Xs[tr*4+2][k];
      const float x3 = Xs[tr*4+3][k];
      acc[0][0] += x0*w4.x; acc[0][1] += x0*w4.y; acc[0][2] += x0*w4.z; acc[0][3] += x0*w4.w;
      acc[1][0] += x1*w4.x; acc[1][1] += x1*w4.y; acc[1][2] += x1*w4.z; acc[1][3] += x1*w4.w;
      acc[2][0] += x2*w4.x; acc[2][1] += x2*w4.y; acc[2][2] += x2*w4.z; acc[2][3] += x2*w4.w;
      acc[3][0] += x3*w4.x; acc[3][1] += x3*w4.y; acc[3][2] += x3*w4.z; acc[3][3] += x3*w4.w;
    }
  }
  float* vp = Vpart + ((size_t)ks * (BB*NN) + r0) * DD;
  #pragma unroll
  for (int i = 0; i < 4; i++) {
    float4 o;  o.x = acc[i][0];  o.y = acc[i][1];  o.z = acc[i][2];  o.w = acc[i][3];
    *(float4*)(vp + (size_t)(4*tr + i) * DD + 4*tc) = o;
  }
}

// -------- Kernel 1b: V = sum(partials)+bv ; q,k scalar scores ---------------
__global__ __launch_bounds__(256) void k_vred(
    const float* __restrict__ Vpart, const float* __restrict__ bv,
    const float* __restrict__ Wq, const float* __restrict__ bq,
    const float* __restrict__ Wk, const float* __restrict__ bk,
    float* __restrict__ V, float* __restrict__ qsg, float* __restrict__ ksg)
{
  __shared__ float Vs[16][DD + 1];
  const int t  = threadIdx.x;
  const size_t e0 = ((size_t)blockIdx.x * 256 + t) * 4;   // float4 granule
  const size_t STR = (size_t)BB * NN * DD;
  float4 a = *(const float4*)(Vpart + e0);
  #pragma unroll
  for (int p = 1; p < KSP; p++) {
    const float4 b = *(const float4*)(Vpart + (size_t)p * STR + e0);
    a.x += b.x;  a.y += b.y;  a.z += b.z;  a.w += b.w;
  }
  const float4 bb = *(const float4*)(bv + (e0 & 63));
  a.x += bb.x;  a.y += bb.y;  a.z += bb.z;  a.w += bb.w;
  *(float4*)(V + e0) = a;
  const int lrow = t >> 4;
  const int lcol = (t * 4) & 63;
  Vs[lrow][lcol]   = a.x;  Vs[lrow][lcol+1] = a.y;
  Vs[lrow][lcol+2] = a.z;  Vs[lrow][lcol+3] = a.w;
  __syncthreads();
  // q,k: 16 rows x 8 heads x {q,k} = 256 tasks, 1 per thread
  const int row = t >> 4;
  const int h   = t & 7;
  const bool isK = (t & 8) != 0;
  const float* W = isK ? Wk : Wq;
  float s = isK ? bk[h] : bq[h];
  #pragma unroll 8
  for (int dd = 0; dd < DD; dd++) s += Vs[row][dd] * W[dd*HH + h];
  const int grow = blockIdx.x * 16 + row;
  const int b = grow >> 11, n = grow & (NN - 1);
  (isK ? ksg : qsg)[(b*HH + h) * NN + n] = s;
}

// ---------------- Kernel 2: bitonic sort of q per (b,h), in-place ------------
// Stages with stride<=64 touch only a wave-owned 128-elem segment: per-wave
// DS ops retire in order -> no barrier needed for those stages.
__global__ __launch_bounds__(1024) void k_sort(
    float* __restrict__ q, unsigned short* __restrict__ idxg)
{
  __shared__ float key[NN];   // 8 KB
  __shared__ int   idx[NN];   // 8 KB
  const int t  = threadIdx.x;
  const int bh = blockIdx.x;
  key[t]        = q[bh*NN + t];        idx[t]        = t;
  key[t + 1024] = q[bh*NN + t + 1024]; idx[t + 1024] = t + 1024;
  __syncthreads();

#define CEX_STAGE(size, stride)                                         \
  {                                                                     \
    const int i = ((t & ~((stride) - 1)) << 1) | (t & ((stride) - 1));  \
    const int j = i + (stride);                                         \
    const bool up = ((i & (size)) == 0);                                \
    const float a = key[i], b = key[j];                                 \
    if (up ? (a > b) : (a < b)) {                                       \
      key[i] = b; key[j] = a;                                           \
      const int tmp = idx[i]; idx[i] = idx[j]; idx[j] = tmp;            \
    }                                                                   \
  }

  // phase A: sizes 2..128 — all strides <=64, wave-local, no barriers
  for (int size = 2; size <= 128; size <<= 1)
    for (int stride = size >> 1; stride > 0; stride >>= 1)
      CEX_STAGE(size, stride)
  __syncthreads();
  // phase B: sizes 256..2048 — barrier only for strides >=128
  for (int size = 256; size <= 2048; size <<= 1) {
    for (int stride = size >> 1; stride >= 128; stride >>= 1) {
      CEX_STAGE(size, stride)
      __syncthreads();
    }
    for (int stride = 64; stride > 0; stride >>= 1)
      CEX_STAGE(size, stride)
    __syncthreads();
  }
#undef CEX_STAGE

  q[bh*NN + t]        = key[t];
  q[bh*NN + t + 1024] = key[t + 1024];
  idxg[bh*NN + t]        = (unsigned short)idx[t];
  idxg[bh*NN + t + 1024] = (unsigned short)idx[t + 1024];
}

// -------- Kernel 3: hierarchical scan — chunk-local prefixes + chunk sums ----
__global__ __launch_bounds__(256) void k_scan(
    const float* __restrict__ sq, const unsigned short* __restrict__ idxg,
    const float* __restrict__ V,
    float* __restrict__ P1, float* __restrict__ P2,
    float* __restrict__ l1, float* __restrict__ l2,
    float* __restrict__ S1g, float* __restrict__ S2g,
    float* __restrict__ SL1, float* __restrict__ SL2)
{
  __shared__ float ss1[4][64], ss2[4][64], sl1[4], sl2[4];
  const int t  = threadIdx.x;
  const int bh = blockIdx.x >> 4;
  const int ck = blockIdx.x & 15;
  const int d  = t & 63, g = t >> 6;
  const int r0 = ck*CKS + g*32;
  const float* Vb  = V + (size_t)(bh >> 3) * NN * DD;
  const float* sqb = sq + bh*NN;
  const unsigned short* ib = idxg + bh*NN;
  float a1 = 0.f, a2 = 0.f, s1 = 0.f, s2 = 0.f;
  #pragma unroll 8
  for (int rr = 0; rr < 32; rr++) {
    const int r = r0 + rr;
    const float qv = sqb[r];
    const float e1 = __expf(qv), e2 = __expf(0.01f*qv);
    const float v  = Vb[(size_t)ib[r]*DD + d];
    a1 += e1*v;  a2 += e2*v;  s1 += e1;  s2 += e2;
  }
  ss1[g][d] = a1;  ss2[g][d] = a2;
  if (d == 0) { sl1[g] = s1;  sl2[g] = s2; }
  __syncthreads();
  float o1 = 0.f, o2 = 0.f, lo1 = 0.f, lo2 = 0.f;
  for (int gg = 0; gg < g; gg++) { o1 += ss1[gg][d]; o2 += ss2[gg][d]; lo1 += sl1[gg]; lo2 += sl2[gg]; }
  if (g == 0) {   // chunk totals -> scratch (lives in d_out, dead before k_out)
    S1g[(bh*NCK + ck)*64 + d] = ss1[0][d]+ss1[1][d]+ss1[2][d]+ss1[3][d];
    S2g[(bh*NCK + ck)*64 + d] = ss2[0][d]+ss2[1][d]+ss2[2][d]+ss2[3][d];
    if (d == 0) {
      SL1[bh*NCK + ck] = sl1[0]+sl1[1]+sl1[2]+sl1[3];
      SL2[bh*NCK + ck] = sl2[0]+sl2[1]+sl2[2]+sl2[3];
    }
  }
  // pass 2: store exclusive chunk-local prefixes (V re-load is L2-hot)
  a1 = o1; a2 = o2; s1 = lo1; s2 = lo2;
  float* P1b = P1 + (size_t)bh*NN*DD;
  float* P2b = P2 + (size_t)bh*NN*DD;
  #pragma unroll 8
  for (int rr = 0; rr < 32; rr++) {
    const int r = r0 + rr;
    const float qv = sqb[r];
    const float e1 = __expf(qv), e2 = __expf(0.01f*qv);
    const float v  = Vb[(size_t)ib[r]*DD + d];
    P1b[(size_t)r*DD + d] = a1;
    P2b[(size_t)r*DD + d] = a2;
    if (d == 0) { l1[bh*NN + r] = s1;  l2[bh*NN + r] = s2; }
    a1 += e1*v;  a2 += e2*v;  s1 += e1;  s2 += e2;
  }
}

// ---------- Kernel 4: fp64 scan of the 16 chunk sums -> chunk offsets --------
__global__ __launch_bounds__(256) void k_off(
    const float* __restrict__ S1g, const float* __restrict__ S2g,
    const float* __restrict__ SL1, const float* __restrict__ SL2,
    float* __restrict__ Off1, float* __restrict__ Off2,
    float* __restrict__ Loff1, float* __restrict__ Loff2)
{
  const int bh = blockIdx.x;
  const int t  = threadIdx.x;
  if (t < 128) {
    const int d = t & 63;
    const bool h2 = t >= 64;
    const float* S = h2 ? S2g : S1g;
    float* O = h2 ? Off2 : Off1;
    double a = 0.0;
    for (int ck = 0; ck < NCK; ck++) {
      O[((size_t)bh*(NCK+1) + ck)*64 + d] = (float)a;
      a += (double)S[((size_t)bh*NCK + ck)*64 + d];
    }
    O[((size_t)bh*(NCK+1) + NCK)*64 + d] = (float)a;
  } else if (t == 128 || t == 129) {
    const bool h2 = (t == 129);
    const float* S = h2 ? SL2 : SL1;
    float* O = h2 ? Loff2 : Loff1;
    double a = 0.0;
    for (int ck = 0; ck < NCK; ck++) { O[bh*(NCK+1) + ck] = (float)a; a += (double)S[bh*NCK + ck]; }
    O[bh*(NCK+1) + NCK] = (float)a;
  }
}

// ------- Kernel 5: 64-ary search (2 rounds) + combine + write ----------------
__global__ __launch_bounds__(256) void k_out(
    const float* __restrict__ sq, const float* __restrict__ ksg,
    const float* __restrict__ P1, const float* __restrict__ P2,
    const float* __restrict__ Off1, const float* __restrict__ Off2,
    const float* __restrict__ l1, const float* __restrict__ l2,
    const float* __restrict__ Loff1, const float* __restrict__ Loff2,
    float* __restrict__ out)
{
  const int t  = threadIdx.x;
  const int bh = blockIdx.x >> 9;
  const int i  = ((blockIdx.x & 511) << 2) + (t >> 6);
  const int d  = t & 63;                      // == lane id within wave
  const int b  = bh >> 3, h = bh & 7;
  const float kv = ksg[bh*NN + i];
  const float tt = -kv;
  const float* s = sq + bh*NN;
  // round 1: lane d probes block-of-32 boundary; sorted => ballot contiguous
  const unsigned long long m1 = __ballot(s[d*32 + 31] <= tt);
  const int c1 = __popcll(m1);
  int pos;
  if (c1 == 64) pos = NN;
  else {
    const int bs = c1 << 5;
    const unsigned long long m2 = __ballot(s[bs + (d & 31)] <= tt);
    pos = bs + (__popcll(m2) >> 1);   // both wave halves probe identically
  }
  const float ek  = __expf(kv);
  const float ek2 = __expf(0.01f * kv);
  const size_t base = (size_t)bh * NN * DD;
  const float T1  = Off1[((size_t)bh*(NCK+1) + NCK)*64 + d];
  const float Lt1 = Loff1[bh*(NCK+1) + NCK];
  float p1v, p2v, q1v, q2v;
  if (pos < NN) {   // wave-uniform
    const int ch = pos >> 7;
    p1v = P1[base + (size_t)pos*DD + d] + Off1[((size_t)bh*(NCK+1) + ch)*64 + d];
    p2v = P2[base + (size_t)pos*DD + d] + Off2[((size_t)bh*(NCK+1) + ch)*64 + d];
    q1v = l1[bh*NN + pos] + Loff1[bh*(NCK+1) + ch];
    q2v = l2[bh*NN + pos] + Loff2[bh*(NCK+1) + ch];
  } else {
    p1v = T1;   p2v = Off2[((size_t)bh*(NCK+1) + NCK)*64 + d];
    q1v = Lt1;  q2v = Loff2[bh*(NCK+1) + NCK];
  }
  const float num = ek * (T1 - p1v)  + ek2 * p2v;
  const float den = ek * (Lt1 - q1v) + ek2 * q2v;
  out[((size_t)(b*NN + i)) * (HH*DD) + h*DD + d] = num / den;
}

extern "C" void kernel_launch(void* const* d_in, const int* in_sizes, int n_in,
                              void* d_out, int out_size, void* d_ws, size_t ws_size,
                              hipStream_t stream)
{
  (void)in_sizes; (void)n_in; (void)out_size; (void)ws_size;
  const float* X  = (const float*)d_in[0];
  const float* Wv = (const float*)d_in[1];
  const float* bv = (const float*)d_in[2];
  const float* Wq = (const float*)d_in[3];
  const float* bq = (const float*)d_in[4];
  const float* Wk = (const float*)d_in[5];
  const float* bk = (const float*)d_in[6];
  float* out = (float*)d_out;

  // workspace carve-up (~36.95 MB, within proven budget)
  float* w = (float*)d_ws;
  float* V     = w;  w += (size_t)BB*NN*DD;        // 524288
  float* qsg   = w;  w += BH*NN;                   // sorted in-place -> sq
  float* ksg   = w;  w += BH*NN;
  float* l1    = w;  w += BH*NN;
  float* l2    = w;  w += BH*NN;
  unsigned short* idxg = (unsigned short*)w;  w += BH*NN/2;   // ushort
  float* Off1  = w;  w += BH*(NCK+1)*DD;
  float* Off2  = w;  w += BH*(NCK+1)*DD;
  float* Loff1 = w;  w += BH*(NCK+1);
  float* Loff2 = w;  w += BH*(NCK+1);
  float* P1    = w;  w += (size_t)BH*NN*DD;        // 4194304 (16 MB)
  float* P2    = w;  w += (size_t)BH*NN*DD;

  // V partials live in P1's space (dead until k_scan): 4 x 2 MB floats = 8 MB
  float* Vpart = P1;

  // chunk-sum scratch lives in d_out: dead before k_out fully overwrites it
  float* S1g = out;                 // 32768
  float* S2g = S1g + BH*NCK*DD;     // 32768
  float* SL1 = S2g + BH*NCK*DD;     // 512
  float* SL2 = SL1 + BH*NCK;        // 512

  k_v    <<<512, 256, 0, stream>>>(X, Wv, Vpart);
  k_vred <<<512, 256, 0, stream>>>(Vpart, bv, Wq, bq, Wk, bk, V, qsg, ksg);
  k_sort <<<BH, 1024, 0, stream>>>(qsg, idxg);
  k_scan <<<BH*NCK, 256, 0, stream>>>(qsg, idxg, V, P1, P2, l1, l2, S1g, S2g, SL1, SL2);
  k_off  <<<BH, 256, 0, stream>>>(S1g, S2g, SL1, SL2, Off1, Off2, Loff1, Loff2);
  k_out  <<<BH*512, 256, 0, stream>>>(qsg, ksg, P1, P2, Off1, Off2, l1, l2, Loff1, Loff2, out);
}